// Round 5
// baseline (462.841 us; speedup 1.0000x reference)
//
#include <hip/hip_runtime.h>
#include <hip/hip_bf16.h>

#define Bn 16
#define Cn 128
#define Hn 128
#define Wn 128
#define HWn (Hn*Wn)
#define CHWn (Cn*HWn)
#define HALF 64
#define NTOT (Bn*HWn)

#define DT_P 76    // Dt pitch in bf16 (152 B: 8B-aligned rows, low-conflict)
#define WL_P 76
#define CB_P 136   // repack pitch in bf16 (272 B: 16B-aligned rows)

typedef __attribute__((ext_vector_type(8))) short short8;
typedef __attribute__((ext_vector_type(4))) float floatx4;

__device__ __forceinline__ float4 fma4(float s, float4 v, float4 a) {
  a.x = fmaf(s, v.x, a.x); a.y = fmaf(s, v.y, a.y);
  a.z = fmaf(s, v.z, a.z); a.w = fmaf(s, v.w, a.w);
  return a;
}
__device__ __forceinline__ unsigned short f2bf(float f) {
  union { __hip_bfloat16 h; unsigned short u; } cv;
  cv.h = __float2bfloat16(f); return cv.u;
}
__device__ __forceinline__ float bf2f(unsigned short u) {
  union { unsigned short u; __hip_bfloat16 h; } cv; cv.u = u;
  return __bfloat162float(cv.h);
}
__device__ __forceinline__ short8 ld_frag(const unsigned short* p) {
  union { uint2 u[2]; short8 s; } cv;
  cv.u[0] = *(const uint2*)p;
  cv.u[1] = *(const uint2*)(p + 4);
  return cv.s;
}

// row contribution with shuffle-sourced halo (row = 32 contiguous lanes)
__device__ __forceinline__ float4 row3(float4 acc, float4 B, float wa, float wb,
                                       float wc, int lane31) {
  float xl = __shfl_up(B.w, 1);
  float xr = __shfl_down(B.x, 1);
  if (lane31 == 0)  xl = 0.f;
  if (lane31 == 31) xr = 0.f;
  float4 L = make_float4(xl, B.x, B.y, B.z);
  float4 R = make_float4(B.y, B.z, B.w, xr);
  acc = fma4(wa, L, acc);
  acc = fma4(wb, B, acc);
  acc = fma4(wc, R, acc);
  return acc;
}

// ======== fused depthwise 3x3 + MFMA pointwise (channels 0..63) ========
// grid: Bn*Hn blocks (one image row each), 256 threads
template<bool BF16>
__global__ __launch_bounds__(256, 3) void dwpw_kernel(
    const float* __restrict__ x, const float* __restrict__ pw_w,
    const float* __restrict__ dw_w, const float* __restrict__ dw_b,
    const float* __restrict__ pw_b, float* __restrict__ outf,
    __hip_bfloat16* __restrict__ outh, float* __restrict__ stats)
{
  __shared__ unsigned short DtCb[128*DT_P]; // 19456 B: Dt[px][k]; reused as Cb[c][px]
  __shared__ unsigned short Wl[64*WL_P];    // 9728 B: bf16 W[c][k]
  __shared__ float dww[640];                // dw weights [j][64] + bias [576+k]
  __shared__ float sred[128];

  const int t = threadIdx.x;
  const int b = blockIdx.x >> 7;
  const int h = blockIdx.x & 127;

  // ---- stage weights ----
  for (int i = t; i < 1024; i += 256) {          // pw_w: 1024 float4s, [c][k]
    int c = i >> 4, k4 = (i & 15) << 2;
    float4 w = ((const float4*)pw_w)[i];
    union { unsigned short us[4]; uint2 u; } cv;
    cv.us[0] = f2bf(w.x); cv.us[1] = f2bf(w.y);
    cv.us[2] = f2bf(w.z); cv.us[3] = f2bf(w.w);
    *(uint2*)&Wl[c*WL_P + k4] = cv.u;
  }
  for (int i = t; i < 576; i += 256) {
    int k = i / 9, j = i - k*9;
    dww[j*64 + k] = dw_w[i];
  }
  if (t < 64)  dww[576 + t] = dw_b[t];
  if (t < 128) sred[t] = 0.f;
  __syncthreads();

  // ---- phase 1: depthwise 3x3 pad=1 -> Dt[px][k] bf16 ----
  {
    const int lane31 = t & 31;
    const int px4 = lane31 << 2;
    const int k0 = t >> 5;             // 0..7 -> k = k0*8 + i
    const float* xb = x + (size_t)b*CHWn + (size_t)h*Wn + px4;
    const bool hasU = (h > 0), hasD = (h < Hn-1);
    const float4 z4 = make_float4(0.f,0.f,0.f,0.f);
    unsigned pkq[4][4];
    unsigned lo[4];
    #pragma unroll
    for (int i = 0; i < 8; ++i) {
      const int k = k0*8 + i;
      const float* xc = xb + (size_t)(2*k)*HWn;
      float4 r0 = hasU ? *(const float4*)(xc - Wn) : z4;
      float4 r1 = *(const float4*)xc;
      float4 r2 = hasD ? *(const float4*)(xc + Wn) : z4;
      float bk = dww[576 + k];
      float4 a = make_float4(bk, bk, bk, bk);
      a = row3(a, r0, dww[0*64+k], dww[1*64+k], dww[2*64+k], lane31);
      a = row3(a, r1, dww[3*64+k], dww[4*64+k], dww[5*64+k], lane31);
      a = row3(a, r2, dww[6*64+k], dww[7*64+k], dww[8*64+k], lane31);
      float av[4] = {a.x, a.y, a.z, a.w};
      if ((i & 1) == 0) {
        #pragma unroll
        for (int j = 0; j < 4; ++j) lo[j] = f2bf(av[j]);
      } else {
        #pragma unroll
        for (int j = 0; j < 4; ++j)
          pkq[j][i>>1] = lo[j] | ((unsigned)f2bf(av[j]) << 16);
      }
    }
    #pragma unroll
    for (int j = 0; j < 4; ++j) {
      unsigned short* p = &DtCb[(px4+j)*DT_P + k0*8];
      uint2 w0; w0.x = pkq[j][0]; w0.y = pkq[j][1];
      uint2 w1; w1.x = pkq[j][2]; w1.y = pkq[j][3];
      *(uint2*)p       = w0;
      *(uint2*)(p + 4) = w1;
    }
  }
  __syncthreads();

  // ---- phase 2: MFMA GEMM  C[64c x 128px] = W[64c x 64k] * D[64k x 128px] ----
  const int lane = t & 63;
  const int wv   = t >> 6;
  const int q4   = lane >> 4;         // quad 0..3
  const int n16  = lane & 15;

  short8 Af[4][2], Bf[2][2];
  #pragma unroll
  for (int ct = 0; ct < 4; ++ct)
    #pragma unroll
    for (int kc = 0; kc < 2; ++kc)
      Af[ct][kc] = ld_frag(&Wl[(ct*16 + n16)*WL_P + kc*32 + q4*8]);
  #pragma unroll
  for (int nt = 0; nt < 2; ++nt)
    #pragma unroll
    for (int kc = 0; kc < 2; ++kc)
      Bf[nt][kc] = ld_frag(&DtCb[(wv*32 + nt*16 + n16)*DT_P + kc*32 + q4*8]);

  floatx4 C[4][2];
  #pragma unroll
  for (int ct = 0; ct < 4; ++ct) {
    float4 bs = *(const float4*)&pw_b[ct*16 + q4*4];
    floatx4 ini = {bs.x, bs.y, bs.z, bs.w};
    C[ct][0] = ini; C[ct][1] = ini;
  }
  #pragma unroll
  for (int kc = 0; kc < 2; ++kc)
    #pragma unroll
    for (int ct = 0; ct < 4; ++ct)
      #pragma unroll
      for (int nt = 0; nt < 2; ++nt)
        C[ct][nt] = __builtin_amdgcn_mfma_f32_16x16x32_bf16(
            Af[ct][kc], Bf[nt][kc], C[ct][nt], 0, 0, 0);

  __syncthreads();   // all frag reads done before Cb overwrite

  // ---- stats (f32 accum): sum over nt + 16 px-lanes via shuffle ----
  {
    float S[4][4], Q[4][4];
    #pragma unroll
    for (int ct = 0; ct < 4; ++ct)
      #pragma unroll
      for (int r = 0; r < 4; ++r) {
        float a = C[ct][0][r], c2 = C[ct][1][r];
        S[ct][r] = a + c2;
        Q[ct][r] = a*a + c2*c2;
      }
    #pragma unroll
    for (int off = 1; off < 16; off <<= 1)
      #pragma unroll
      for (int ct = 0; ct < 4; ++ct)
        #pragma unroll
        for (int r = 0; r < 4; ++r) {
          S[ct][r] += __shfl_xor(S[ct][r], off);
          Q[ct][r] += __shfl_xor(Q[ct][r], off);
        }
    if (n16 == 0) {
      #pragma unroll
      for (int ct = 0; ct < 4; ++ct)
        #pragma unroll
        for (int r = 0; r < 4; ++r) {
          int c = ct*16 + q4*4 + r;
          atomicAdd(&sred[c], S[ct][r]);
          atomicAdd(&sred[64 + c], Q[ct][r]);
        }
    }
  }

  // ---- repack C -> Cb[c][px] bf16 (or direct f32 store fallback) ----
  const size_t ob = (size_t)b*CHWn + (size_t)h*Wn;
  if (BF16) {
    #pragma unroll
    for (int ct = 0; ct < 4; ++ct)
      #pragma unroll
      for (int nt = 0; nt < 2; ++nt)
        #pragma unroll
        for (int r = 0; r < 4; ++r) {
          int c  = ct*16 + q4*4 + r;
          int px = wv*32 + nt*16 + n16;
          DtCb[c*CB_P + px] = f2bf(C[ct][nt][r]);
        }
  } else {
    #pragma unroll
    for (int ct = 0; ct < 4; ++ct)
      #pragma unroll
      for (int nt = 0; nt < 2; ++nt)
        #pragma unroll
        for (int r = 0; r < 4; ++r) {
          int c  = ct*16 + q4*4 + r;
          int px = wv*32 + nt*16 + n16;
          outf[ob + (size_t)c*HWn + px] = C[ct][nt][r];
        }
  }
  __syncthreads();

  if (BF16) {
    for (int i = t; i < 1024; i += 256) {     // 64c x 16 chunks of 8 bf16
      int c = i >> 4, p8 = (i & 15) << 3;
      uint4 v = *(const uint4*)&DtCb[c*CB_P + p8];
      *(uint4*)(outh + ob + (size_t)c*HWn + p8) = v;
    }
  }
  if (t < 64)       atomicAdd(&stats[t], sred[t]);
  else if (t < 128) atomicAdd(&stats[64 + t], sred[t]);  // -> stats[128 + (t-64)]
}

// ======== dilated depthwise, streaming (channels 64..127) ========
template<int D> __device__ __forceinline__ float4 shiftL(float4 A, float4 B) {
  if (D == 1) return make_float4(A.w, B.x, B.y, B.z);
  if (D == 2) return make_float4(A.z, A.w, B.x, B.y);
  if (D == 3) return make_float4(A.y, A.z, A.w, B.x);
  return A;
}
template<int D> __device__ __forceinline__ float4 shiftR(float4 B, float4 C) {
  if (D == 1) return make_float4(B.y, B.z, B.w, C.x);
  if (D == 2) return make_float4(B.z, B.w, C.x, C.y);
  if (D == 3) return make_float4(B.w, C.x, C.y, C.z);
  return C;
}

template<bool BF16, int D>
__device__ __forceinline__ void mcc_row(
    const float* __restrict__ xc, const float* __restrict__ wj, float bj,
    float* __restrict__ outf, __hip_bfloat16* __restrict__ outh,
    int h, int px4, float& s, float& q)
{
  const float4 z4 = make_float4(0.f,0.f,0.f,0.f);
  float4 acc = make_float4(bj, bj, bj, bj);
  #pragma unroll
  for (int dr = 0; dr < 3; ++dr) {
    int rr = h + (dr-1)*D;
    if (rr >= 0 && rr < Hn) {
      const float* rp = xc + rr*Wn;
      float4 Bc = *(const float4*)(rp + px4);
      float4 Ac = (px4 > 0)   ? *(const float4*)(rp + px4 - 4) : z4;
      float4 Cc = (px4 < 124) ? *(const float4*)(rp + px4 + 4) : z4;
      acc = fma4(wj[dr*3+0], shiftL<D>(Ac, Bc), acc);
      acc = fma4(wj[dr*3+1], Bc, acc);
      acc = fma4(wj[dr*3+2], shiftR<D>(Bc, Cc), acc);
    }
  }
  if (BF16) {
    uint2 pk;
    pk.x = (unsigned)f2bf(acc.x) | ((unsigned)f2bf(acc.y) << 16);
    pk.y = (unsigned)f2bf(acc.z) | ((unsigned)f2bf(acc.w) << 16);
    *(uint2*)(outh + (size_t)h*Wn + px4) = pk;
  } else {
    *(float4*)(outf + (size_t)h*Wn + px4) = acc;
  }
  s = acc.x + acc.y + acc.z + acc.w;
  q = acc.x*acc.x + acc.y*acc.y + acc.z*acc.z + acc.w*acc.w;
}

// grid: Bn*64*(Hn/8) = 16384 blocks; block = (b, m, 8-row tile); no staging LDS
template<bool BF16>
__global__ __launch_bounds__(256) void mcc_kernel(
    const float* __restrict__ x, const float* __restrict__ mcc_w,
    const float* __restrict__ mcc_b, float* __restrict__ outf,
    __hip_bfloat16* __restrict__ outh, float* __restrict__ stats)
{
  __shared__ float red[8];
  const int t  = threadIdx.x;
  const int hb = blockIdx.x & 15;
  const int m  = (blockIdx.x >> 4) & 63;
  const int b  = blockIdx.x >> 10;
  const int j  = m & 3;
  const int h  = (hb << 3) + (t >> 5);
  const int px4 = (t & 31) << 2;

  const float* xc = x + (size_t)b*CHWn + (size_t)(2*m+1)*HWn;
  const size_t oo = (size_t)b*CHWn + (size_t)(HALF+m)*HWn;
  float* of = BF16 ? nullptr : outf + oo;
  __hip_bfloat16* oh = BF16 ? outh + oo : nullptr;
  const float* wj = mcc_w + j*9;
  const float bj = mcc_b[j];

  float s = 0.f, q = 0.f;
  switch (j) {
    case 0:  mcc_row<BF16,1>(xc, wj, bj, of, oh, h, px4, s, q); break;
    case 1:  mcc_row<BF16,2>(xc, wj, bj, of, oh, h, px4, s, q); break;
    case 2:  mcc_row<BF16,3>(xc, wj, bj, of, oh, h, px4, s, q); break;
    default: mcc_row<BF16,4>(xc, wj, bj, of, oh, h, px4, s, q); break;
  }

  #pragma unroll
  for (int off = 32; off > 0; off >>= 1) {
    s += __shfl_down(s, off);
    q += __shfl_down(q, off);
  }
  const int wvi = t >> 6;
  if ((t & 63) == 0) { red[wvi] = s; red[4+wvi] = q; }
  __syncthreads();
  if (t == 0) {
    atomicAdd(&stats[HALF + m],       red[0]+red[1]+red[2]+red[3]);
    atomicAdd(&stats[128 + HALF + m], red[4]+red[5]+red[6]+red[7]);
  }
}

// ======== normalize + relu: one block per (b,c) plane ========
__global__ __launch_bounds__(256) void norm_bf_kernel(
    const unsigned short* __restrict__ inh, float* __restrict__ out,
    const float* __restrict__ stats, const float* __restrict__ gamma,
    const float* __restrict__ beta)
{
  const int plane = blockIdx.x;          // 2048 = b*128 + c
  const int c = plane & 127;
  const float n = (float)NTOT;
  float mean = stats[c] / n;
  float var  = stats[128 + c] / n - mean*mean;
  float sc = gamma[c] / sqrtf(var + 1e-5f);
  float sh = beta[c] - mean * sc;

  const uint4* in = (const uint4*)(inh + (size_t)plane*HWn);
  float* op = out + (size_t)plane*HWn;
  #pragma unroll
  for (int i = 0; i < 8; ++i) {
    int idx = threadIdx.x + i*256;       // 2048 uint4 per plane
    uint4 p = in[idx];
    float4 a, bq;
    a.x = fmaxf(fmaf(bf2f(p.x & 0xffff), sc, sh), 0.f);
    a.y = fmaxf(fmaf(bf2f(p.x >> 16),    sc, sh), 0.f);
    a.z = fmaxf(fmaf(bf2f(p.y & 0xffff), sc, sh), 0.f);
    a.w = fmaxf(fmaf(bf2f(p.y >> 16),    sc, sh), 0.f);
    bq.x = fmaxf(fmaf(bf2f(p.z & 0xffff), sc, sh), 0.f);
    bq.y = fmaxf(fmaf(bf2f(p.z >> 16),    sc, sh), 0.f);
    bq.z = fmaxf(fmaf(bf2f(p.w & 0xffff), sc, sh), 0.f);
    bq.w = fmaxf(fmaf(bf2f(p.w >> 16),    sc, sh), 0.f);
    *(float4*)(op + idx*8)     = a;
    *(float4*)(op + idx*8 + 4) = bq;
  }
}

__global__ __launch_bounds__(256) void norm_f32_kernel(float* __restrict__ out,
    const float* __restrict__ stats, const float* __restrict__ gamma,
    const float* __restrict__ beta)
{
  const int plane = blockIdx.x;
  const int c = plane & 127;
  const float n = (float)NTOT;
  float mean = stats[c] / n;
  float var  = stats[128 + c] / n - mean*mean;
  float sc = gamma[c] / sqrtf(var + 1e-5f);
  float sh = beta[c] - mean * sc;
  float* op = out + (size_t)plane*HWn;
  #pragma unroll
  for (int i = 0; i < 16; ++i) {
    int idx = threadIdx.x + i*256;       // 4096 float4 per plane
    float4 v = ((const float4*)op)[idx];
    v.x = fmaxf(fmaf(v.x, sc, sh), 0.f);
    v.y = fmaxf(fmaf(v.y, sc, sh), 0.f);
    v.z = fmaxf(fmaf(v.z, sc, sh), 0.f);
    v.w = fmaxf(fmaf(v.w, sc, sh), 0.f);
    ((float4*)op)[idx] = v;
  }
}

extern "C" void kernel_launch(void* const* d_in, const int* in_sizes, int n_in,
                              void* d_out, int out_size, void* d_ws, size_t ws_size,
                              hipStream_t stream)
{
  (void)in_sizes; (void)n_in; (void)out_size;
  const float* x     = (const float*)d_in[0];
  const float* dw_w  = (const float*)d_in[1];
  const float* dw_b  = (const float*)d_in[2];
  const float* pw_w  = (const float*)d_in[3];
  const float* pw_b  = (const float*)d_in[4];
  const float* mcc_w = (const float*)d_in[5];
  const float* mcc_b = (const float*)d_in[6];
  const float* gamma = (const float*)d_in[7];
  const float* beta  = (const float*)d_in[8];
  float* out   = (float*)d_out;
  float* stats = (float*)d_ws;                        // 256 floats
  __hip_bfloat16* bf = (__hip_bfloat16*)((char*)d_ws + 1024);
  const size_t need = 1024 + (size_t)Bn*CHWn*2;
  const bool useBF = ws_size >= need;

  hipMemsetAsync(d_ws, 0, 1024, stream);
  if (useBF) {
    dwpw_kernel<true><<<Bn*Hn, 256, 0, stream>>>(x, pw_w, dw_w, dw_b, pw_b, nullptr, bf, stats);
    mcc_kernel<true><<<Bn*HALF*(Hn/8), 256, 0, stream>>>(x, mcc_w, mcc_b, nullptr, bf, stats);
    norm_bf_kernel<<<Bn*Cn, 256, 0, stream>>>((const unsigned short*)bf, out, stats, gamma, beta);
  } else {
    dwpw_kernel<false><<<Bn*Hn, 256, 0, stream>>>(x, pw_w, dw_w, dw_b, pw_b, out, nullptr, stats);
    mcc_kernel<false><<<Bn*HALF*(Hn/8), 256, 0, stream>>>(x, mcc_w, mcc_b, out, nullptr, stats);
    norm_f32_kernel<<<Bn*Cn, 256, 0, stream>>>(out, stats, gamma, beta);
  }
}

// Round 6
// 368.157 us; speedup vs baseline: 1.2572x; 1.2572x over previous
//
#include <hip/hip_runtime.h>
#include <hip/hip_bf16.h>

#define Bn 16
#define Cn 128
#define Hn 128
#define Wn 128
#define HWn (Hn*Wn)
#define CHWn (Cn*HWn)
#define HALF 64
#define NTOT (Bn*HWn)

#define DT_P 76    // Dt pitch in bf16 (152 B: 8B-aligned rows, low-conflict)
#define WL_P 76
#define CB_P 136   // repack pitch in bf16 (272 B: 16B-aligned rows)

typedef __attribute__((ext_vector_type(8))) short short8;
typedef __attribute__((ext_vector_type(4))) float floatx4;

__device__ __forceinline__ float4 fma4(float s, float4 v, float4 a) {
  a.x = fmaf(s, v.x, a.x); a.y = fmaf(s, v.y, a.y);
  a.z = fmaf(s, v.z, a.z); a.w = fmaf(s, v.w, a.w);
  return a;
}
__device__ __forceinline__ unsigned short f2bf(float f) {
  union { __hip_bfloat16 h; unsigned short u; } cv;
  cv.h = __float2bfloat16(f); return cv.u;
}
__device__ __forceinline__ float bf2f(unsigned short u) {
  union { unsigned short u; __hip_bfloat16 h; } cv; cv.u = u;
  return __bfloat162float(cv.h);
}
__device__ __forceinline__ unsigned pk2f(float a, float b) {
  return (unsigned)f2bf(a) | ((unsigned)f2bf(b) << 16);
}
__device__ __forceinline__ short8 ld_frag(const unsigned short* p) {
  union { uint2 u[2]; short8 s; } cv;
  cv.u[0] = *(const uint2*)p;
  cv.u[1] = *(const uint2*)(p + 4);
  return cv.s;
}

// row contribution with shuffle-sourced halo (row = 32 contiguous lanes)
__device__ __forceinline__ float4 row3(float4 acc, float4 B, float wa, float wb,
                                       float wc, int lane31) {
  float xl = __shfl_up(B.w, 1);
  float xr = __shfl_down(B.x, 1);
  if (lane31 == 0)  xl = 0.f;
  if (lane31 == 31) xr = 0.f;
  float4 L = make_float4(xl, B.x, B.y, B.z);
  float4 R = make_float4(B.y, B.z, B.w, xr);
  acc = fma4(wa, L, acc);
  acc = fma4(wb, B, acc);
  acc = fma4(wc, R, acc);
  return acc;
}

// ======== fused depthwise 3x3 + MFMA pointwise (channels 0..63) ========
// grid: Bn*Hn blocks (one image row each), 256 threads
// NOTE: (256,2) not (256,3): at 3 waves/EU the unified VGPR budget (~170)
// forces ~50 regs/thread of scratch spill (R5: +100 MB HBM round-trip).
template<bool BF16>
__global__ __launch_bounds__(256, 2) void dwpw_kernel(
    const float* __restrict__ x, const float* __restrict__ pw_w,
    const float* __restrict__ dw_w, const float* __restrict__ dw_b,
    const float* __restrict__ pw_b, float* __restrict__ outf,
    __hip_bfloat16* __restrict__ outh, float* __restrict__ stats)
{
  __shared__ unsigned short DtCb[128*DT_P]; // 19456 B: Dt[px][k]; reused as Cb[c][px]
  __shared__ unsigned short Wl[64*WL_P];    // 9728 B: bf16 W[c][k]
  __shared__ float dww[640];                // dw weights [j][64] + bias [576+k]
  __shared__ float sred[128];

  const int t = threadIdx.x;
  const int b = blockIdx.x >> 7;
  const int h = blockIdx.x & 127;

  // ---- stage weights ----
  for (int i = t; i < 1024; i += 256) {          // pw_w: 1024 float4s, [c][k]
    int c = i >> 4, k4 = (i & 15) << 2;
    float4 w = ((const float4*)pw_w)[i];
    union { unsigned short us[4]; uint2 u; } cv;
    cv.us[0] = f2bf(w.x); cv.us[1] = f2bf(w.y);
    cv.us[2] = f2bf(w.z); cv.us[3] = f2bf(w.w);
    *(uint2*)&Wl[c*WL_P + k4] = cv.u;
  }
  for (int i = t; i < 576; i += 256) {
    int k = i / 9, j = i - k*9;
    dww[j*64 + k] = dw_w[i];
  }
  if (t < 64)  dww[576 + t] = dw_b[t];
  if (t < 128) sred[t] = 0.f;
  __syncthreads();

  // ---- phase 1: depthwise 3x3 pad=1 -> Dt[px][k] bf16 ----
  {
    const int lane31 = t & 31;
    const int px4 = lane31 << 2;
    const int k0 = t >> 5;             // 0..7 -> k = k0*8 + i
    const float* xb = x + (size_t)b*CHWn + (size_t)h*Wn + px4;
    const bool hasU = (h > 0), hasD = (h < Hn-1);
    const float4 z4 = make_float4(0.f,0.f,0.f,0.f);
    unsigned pkq[4][4];
    unsigned lo[4];
    #pragma unroll
    for (int i = 0; i < 8; ++i) {
      const int k = k0*8 + i;
      const float* xc = xb + (size_t)(2*k)*HWn;
      float4 r0 = hasU ? *(const float4*)(xc - Wn) : z4;
      float4 r1 = *(const float4*)xc;
      float4 r2 = hasD ? *(const float4*)(xc + Wn) : z4;
      float bk = dww[576 + k];
      float4 a = make_float4(bk, bk, bk, bk);
      a = row3(a, r0, dww[0*64+k], dww[1*64+k], dww[2*64+k], lane31);
      a = row3(a, r1, dww[3*64+k], dww[4*64+k], dww[5*64+k], lane31);
      a = row3(a, r2, dww[6*64+k], dww[7*64+k], dww[8*64+k], lane31);
      float av[4] = {a.x, a.y, a.z, a.w};
      if ((i & 1) == 0) {
        #pragma unroll
        for (int j = 0; j < 4; ++j) lo[j] = f2bf(av[j]);
      } else {
        #pragma unroll
        for (int j = 0; j < 4; ++j)
          pkq[j][i>>1] = lo[j] | ((unsigned)f2bf(av[j]) << 16);
      }
    }
    #pragma unroll
    for (int j = 0; j < 4; ++j) {
      unsigned short* p = &DtCb[(px4+j)*DT_P + k0*8];
      uint2 w0; w0.x = pkq[j][0]; w0.y = pkq[j][1];
      uint2 w1; w1.x = pkq[j][2]; w1.y = pkq[j][3];
      *(uint2*)p       = w0;
      *(uint2*)(p + 4) = w1;
    }
  }
  __syncthreads();

  // ---- phase 2: MFMA GEMM  C[64c x 128px] = W[64c x 64k] * D[64k x 128px] ----
  const int lane = t & 63;
  const int wv   = t >> 6;
  const int q4   = lane >> 4;         // quad 0..3
  const int n16  = lane & 15;

  short8 Af[4][2], Bf[2][2];
  #pragma unroll
  for (int ct = 0; ct < 4; ++ct)
    #pragma unroll
    for (int kc = 0; kc < 2; ++kc)
      Af[ct][kc] = ld_frag(&Wl[(ct*16 + n16)*WL_P + kc*32 + q4*8]);
  #pragma unroll
  for (int nt = 0; nt < 2; ++nt)
    #pragma unroll
    for (int kc = 0; kc < 2; ++kc)
      Bf[nt][kc] = ld_frag(&DtCb[(wv*32 + nt*16 + n16)*DT_P + kc*32 + q4*8]);

  floatx4 C[4][2];
  #pragma unroll
  for (int ct = 0; ct < 4; ++ct) {
    float4 bs = *(const float4*)&pw_b[ct*16 + q4*4];
    floatx4 ini = {bs.x, bs.y, bs.z, bs.w};
    C[ct][0] = ini; C[ct][1] = ini;
  }
  #pragma unroll
  for (int kc = 0; kc < 2; ++kc)
    #pragma unroll
    for (int ct = 0; ct < 4; ++ct)
      #pragma unroll
      for (int nt = 0; nt < 2; ++nt)
        C[ct][nt] = __builtin_amdgcn_mfma_f32_16x16x32_bf16(
            Af[ct][kc], Bf[nt][kc], C[ct][nt], 0, 0, 0);

  __syncthreads();   // all frag reads done before Cb overwrite

  // ---- stats: per-ct (small live range), 16-lane shuffle, LDS atomic ----
  #pragma unroll
  for (int ct = 0; ct < 4; ++ct) {
    float S[4], Q[4];
    #pragma unroll
    for (int r = 0; r < 4; ++r) {
      float a = C[ct][0][r], c2 = C[ct][1][r];
      S[r] = a + c2;
      Q[r] = a*a + c2*c2;
    }
    #pragma unroll
    for (int off = 1; off < 16; off <<= 1)
      #pragma unroll
      for (int r = 0; r < 4; ++r) {
        S[r] += __shfl_xor(S[r], off);
        Q[r] += __shfl_xor(Q[r], off);
      }
    if (n16 == 0) {
      #pragma unroll
      for (int r = 0; r < 4; ++r) {
        int c = ct*16 + q4*4 + r;
        atomicAdd(&sred[c], S[r]);
        atomicAdd(&sred[64 + c], Q[r]);
      }
    }
  }

  // ---- repack C -> Cb[c][px] bf16 (or direct f32 store fallback) ----
  const size_t ob = (size_t)b*CHWn + (size_t)h*Wn;
  if (BF16) {
    #pragma unroll
    for (int ct = 0; ct < 4; ++ct)
      #pragma unroll
      for (int nt = 0; nt < 2; ++nt)
        #pragma unroll
        for (int r = 0; r < 4; ++r) {
          int c  = ct*16 + q4*4 + r;
          int px = wv*32 + nt*16 + n16;
          DtCb[c*CB_P + px] = f2bf(C[ct][nt][r]);
        }
  } else {
    #pragma unroll
    for (int ct = 0; ct < 4; ++ct)
      #pragma unroll
      for (int nt = 0; nt < 2; ++nt)
        #pragma unroll
        for (int r = 0; r < 4; ++r) {
          int c  = ct*16 + q4*4 + r;
          int px = wv*32 + nt*16 + n16;
          outf[ob + (size_t)c*HWn + px] = C[ct][nt][r];
        }
  }
  __syncthreads();

  if (BF16) {
    for (int i = t; i < 1024; i += 256) {     // 64c x 16 chunks of 8 bf16
      int c = i >> 4, p8 = (i & 15) << 3;
      uint4 v = *(const uint4*)&DtCb[c*CB_P + p8];
      *(uint4*)(outh + ob + (size_t)c*HWn + p8) = v;
    }
  }
  if (t < 64)       atomicAdd(&stats[t], sred[t]);
  else if (t < 128) atomicAdd(&stats[64 + t], sred[t]);  // -> stats[128 + (t-64)]
}

// ======== dilated depthwise (channels 64..127), R4 LDS-staged version ========
template<int D> __device__ __forceinline__ float4 shiftL(float4 A, float4 B) {
  if (D == 1) return make_float4(A.w, B.x, B.y, B.z);
  if (D == 2) return make_float4(A.z, A.w, B.x, B.y);
  if (D == 3) return make_float4(A.y, A.z, A.w, B.x);
  return A;
}
template<int D> __device__ __forceinline__ float4 shiftR(float4 B, float4 C) {
  if (D == 1) return make_float4(B.y, B.z, B.w, C.x);
  if (D == 2) return make_float4(B.z, B.w, C.x, C.y);
  if (D == 3) return make_float4(B.w, C.x, C.y, C.z);
  return C;
}

template<bool BF16, int D>
__device__ __forceinline__ void mcc_compute(
    const float* __restrict__ xc, const float* __restrict__ wj, float bj,
    float* __restrict__ outf, __hip_bfloat16* __restrict__ outh,
    float* lds, int t, int h0, float& s, float& q)
{
  const int R = 16 + 2*D;
  for (int idx = t; idx < R*32; idx += 256) {
    int r = idx >> 5, p4 = (idx & 31) << 2;
    int gr = h0 - D + r;
    float4 v = make_float4(0.f,0.f,0.f,0.f);
    if (gr >= 0 && gr < Hn) v = *(const float4*)(xc + gr*Wn + p4);
    *(float4*)&lds[r*128 + p4] = v;
  }
  __syncthreads();
  const int px4 = (t & 31) << 2;
  const int rl  = t >> 5;            // 0..7
  s = 0.f; q = 0.f;
  #pragma unroll
  for (int rr = 0; rr < 2; ++rr) {
    const int row = rl + rr*8;       // 0..15
    float4 acc = make_float4(bj, bj, bj, bj);
    #pragma unroll
    for (int dr = 0; dr < 3; ++dr) {
      const float* lrow = &lds[(row + dr*D)*128];
      float4 B4 = *(const float4*)(lrow + px4);
      float4 A4 = make_float4(0.f,0.f,0.f,0.f);
      float4 C4 = make_float4(0.f,0.f,0.f,0.f);
      if (px4 > 0)   A4 = *(const float4*)(lrow + px4 - 4);
      if (px4 < 124) C4 = *(const float4*)(lrow + px4 + 4);
      acc = fma4(wj[dr*3+0], shiftL<D>(A4, B4), acc);
      acc = fma4(wj[dr*3+1], B4, acc);
      acc = fma4(wj[dr*3+2], shiftR<D>(B4, C4), acc);
    }
    if (BF16) {
      uint2 pk; pk.x = pk2f(acc.x, acc.y); pk.y = pk2f(acc.z, acc.w);
      *(uint2*)(outh + (size_t)(h0+row)*Wn + px4) = pk;
    } else {
      *(float4*)(outf + (size_t)(h0+row)*Wn + px4) = acc;
    }
    s += acc.x + acc.y + acc.z + acc.w;
    q += acc.x*acc.x + acc.y*acc.y + acc.z*acc.z + acc.w*acc.w;
  }
}

// grid: Bn * 64 * (Hn/16) = 8192 blocks; block = (b, m, 16-row tile)
template<bool BF16>
__global__ __launch_bounds__(256) void mcc_kernel(
    const float* __restrict__ x, const float* __restrict__ mcc_w,
    const float* __restrict__ mcc_b, float* __restrict__ outf,
    __hip_bfloat16* __restrict__ outh, float* __restrict__ stats)
{
  __shared__ float lds[24*128];
  __shared__ float red[8];
  const int t  = threadIdx.x;
  const int hb = blockIdx.x & 7;
  const int m  = (blockIdx.x >> 3) & 63;
  const int b  = blockIdx.x >> 9;
  const int j  = m & 3;
  const int h0 = hb << 4;

  const float* xc = x + (size_t)b*CHWn + (size_t)(2*m+1)*HWn;
  const size_t oo = (size_t)b*CHWn + (size_t)(HALF+m)*HWn;
  float* of = BF16 ? nullptr : outf + oo;
  __hip_bfloat16* oh = BF16 ? outh + oo : nullptr;
  const float* wj = mcc_w + j*9;
  const float bj = mcc_b[j];

  float s = 0.f, q = 0.f;
  switch (j) {
    case 0:  mcc_compute<BF16,1>(xc, wj, bj, of, oh, lds, t, h0, s, q); break;
    case 1:  mcc_compute<BF16,2>(xc, wj, bj, of, oh, lds, t, h0, s, q); break;
    case 2:  mcc_compute<BF16,3>(xc, wj, bj, of, oh, lds, t, h0, s, q); break;
    default: mcc_compute<BF16,4>(xc, wj, bj, of, oh, lds, t, h0, s, q); break;
  }

  #pragma unroll
  for (int off = 32; off > 0; off >>= 1) {
    s += __shfl_down(s, off);
    q += __shfl_down(q, off);
  }
  const int wvi = t >> 6;
  if ((t & 63) == 0) { red[wvi] = s; red[4+wvi] = q; }
  __syncthreads();
  if (t == 0) {
    atomicAdd(&stats[HALF + m],       red[0]+red[1]+red[2]+red[3]);
    atomicAdd(&stats[128 + HALF + m], red[4]+red[5]+red[6]+red[7]);
  }
}

// ======== normalize + relu: 2 blocks per (b,c) plane ========
__global__ __launch_bounds__(256) void norm_bf_kernel(
    const unsigned short* __restrict__ inh, float* __restrict__ out,
    const float* __restrict__ stats, const float* __restrict__ gamma,
    const float* __restrict__ beta)
{
  const int blk = blockIdx.x;            // 4096 = plane*2 + half
  const int plane = blk >> 1;
  const int half = blk & 1;
  const int c = plane & 127;
  const float n = (float)NTOT;
  float mean = stats[c] / n;
  float var  = stats[128 + c] / n - mean*mean;
  float sc = gamma[c] / sqrtf(var + 1e-5f);
  float sh = beta[c] - mean * sc;

  const uint4* in = (const uint4*)(inh + (size_t)plane*HWn) + half*1024;
  float* op = out + (size_t)plane*HWn + half*8192;
  #pragma unroll
  for (int i = 0; i < 4; ++i) {
    int idx = threadIdx.x + i*256;       // 1024 uint4 per half-plane
    uint4 p = in[idx];
    float4 a, bq;
    a.x = fmaxf(fmaf(bf2f(p.x & 0xffff), sc, sh), 0.f);
    a.y = fmaxf(fmaf(bf2f(p.x >> 16),    sc, sh), 0.f);
    a.z = fmaxf(fmaf(bf2f(p.y & 0xffff), sc, sh), 0.f);
    a.w = fmaxf(fmaf(bf2f(p.y >> 16),    sc, sh), 0.f);
    bq.x = fmaxf(fmaf(bf2f(p.z & 0xffff), sc, sh), 0.f);
    bq.y = fmaxf(fmaf(bf2f(p.z >> 16),    sc, sh), 0.f);
    bq.z = fmaxf(fmaf(bf2f(p.w & 0xffff), sc, sh), 0.f);
    bq.w = fmaxf(fmaf(bf2f(p.w >> 16),    sc, sh), 0.f);
    *(float4*)(op + idx*8)     = a;
    *(float4*)(op + idx*8 + 4) = bq;
  }
}

__global__ __launch_bounds__(256) void norm_f32_kernel(float* __restrict__ out,
    const float* __restrict__ stats, const float* __restrict__ gamma,
    const float* __restrict__ beta)
{
  const int blk = blockIdx.x;
  const int plane = blk >> 1;
  const int half = blk & 1;
  const int c = plane & 127;
  const float n = (float)NTOT;
  float mean = stats[c] / n;
  float var  = stats[128 + c] / n - mean*mean;
  float sc = gamma[c] / sqrtf(var + 1e-5f);
  float sh = beta[c] - mean * sc;
  float* op = out + (size_t)plane*HWn + half*8192;
  #pragma unroll
  for (int i = 0; i < 8; ++i) {
    int idx = threadIdx.x + i*256;       // 2048 float4 per half-plane
    float4 v = ((const float4*)op)[idx];
    v.x = fmaxf(fmaf(v.x, sc, sh), 0.f);
    v.y = fmaxf(fmaf(v.y, sc, sh), 0.f);
    v.z = fmaxf(fmaf(v.z, sc, sh), 0.f);
    v.w = fmaxf(fmaf(v.w, sc, sh), 0.f);
    ((float4*)op)[idx] = v;
  }
}

extern "C" void kernel_launch(void* const* d_in, const int* in_sizes, int n_in,
                              void* d_out, int out_size, void* d_ws, size_t ws_size,
                              hipStream_t stream)
{
  (void)in_sizes; (void)n_in; (void)out_size;
  const float* x     = (const float*)d_in[0];
  const float* dw_w  = (const float*)d_in[1];
  const float* dw_b  = (const float*)d_in[2];
  const float* pw_w  = (const float*)d_in[3];
  const float* pw_b  = (const float*)d_in[4];
  const float* mcc_w = (const float*)d_in[5];
  const float* mcc_b = (const float*)d_in[6];
  const float* gamma = (const float*)d_in[7];
  const float* beta  = (const float*)d_in[8];
  float* out   = (float*)d_out;
  float* stats = (float*)d_ws;                        // 256 floats
  __hip_bfloat16* bf = (__hip_bfloat16*)((char*)d_ws + 1024);
  const size_t need = 1024 + (size_t)Bn*CHWn*2;
  const bool useBF = ws_size >= need;

  hipMemsetAsync(d_ws, 0, 1024, stream);
  if (useBF) {
    dwpw_kernel<true><<<Bn*Hn, 256, 0, stream>>>(x, pw_w, dw_w, dw_b, pw_b, nullptr, bf, stats);
    mcc_kernel<true><<<Bn*HALF*(Hn/16), 256, 0, stream>>>(x, mcc_w, mcc_b, nullptr, bf, stats);
    norm_bf_kernel<<<Bn*Cn*2, 256, 0, stream>>>((const unsigned short*)bf, out, stats, gamma, beta);
  } else {
    dwpw_kernel<false><<<Bn*Hn, 256, 0, stream>>>(x, pw_w, dw_w, dw_b, pw_b, out, nullptr, stats);
    mcc_kernel<false><<<Bn*HALF*(Hn/16), 256, 0, stream>>>(x, mcc_w, mcc_b, out, nullptr, stats);
    norm_f32_kernel<<<Bn*Cn*2, 256, 0, stream>>>(out, stats, gamma, beta);
  }
}